// Round 7
// baseline (361.919 us; speedup 1.0000x reference)
//
#include <hip/hip_runtime.h>
#include <hip/hip_bf16.h>

typedef __attribute__((ext_vector_type(8))) short short8;
typedef __attribute__((ext_vector_type(4))) float f32x4;

// SCALE * log2(e), folded into Ql at store time; flash uses exp2 directly.
#define QSCALE 0.18033688011112042f

__device__ __forceinline__ unsigned short f2bf(float f){
    unsigned u = __float_as_uint(f);
    unsigned r = (u + 0x7fffu + ((u>>16)&1u))>>16;
    return (unsigned short)r;
}
__device__ __forceinline__ unsigned pk_rtne(float hi, float lo){
    return (((unsigned)f2bf(hi))<<16) | (unsigned)f2bf(lo);
}

// ---------------- out = x_l + x_r ----------------
__global__ __launch_bounds__(256) void init_out_k(const float* __restrict__ xl,
                                                  const float* __restrict__ xr,
                                                  float* __restrict__ out, int n4){
    int i = blockIdx.x*256 + threadIdx.x;
    if (i < n4){
        const float4* a = (const float4*)xl;
        const float4* b = (const float4*)xr;
        float4 va = a[i], vb = b[i];
        float4 vo; vo.x=va.x+vb.x; vo.y=va.y+vb.y; vo.z=va.z+vb.z; vo.w=va.w+vb.w;
        ((float4*)out)[i] = vo;
    }
}

// ---------------- fused conv1x1 (MFMA, with halo) + depthwise 3x3, one side ----------------
// Block = 64w x 64c tile at fixed (b,h). Stages x^T halo tile (3 h-rows x 66 w x 64 c) in LDS,
// runs dual conv1x1 via MFMA into sT (LDS only, no global T), then 3x3 dwconv from sT with
// coordinate-validity (zero-padding: invalid taps skipped). Set 0 -> Q [b,hw,c] (scaled),
// set 1 -> V [b,c,hw]. grid: b(2)*h(128)*wt(8) = 2048 blocks x 256 threads.
#define FM 208   // 13 m-tiles of 16 (198 used)
__global__ __launch_bounds__(256) void fused_proj_k(
    const float* __restrict__ x,
    const float* __restrict__ w1, const float* __restrict__ b1,
    const float* __restrict__ wd1, const float* __restrict__ bd1,
    const float* __restrict__ w2, const float* __restrict__ b2,
    const float* __restrict__ wd2, const float* __restrict__ bd2,
    unsigned short* __restrict__ Qdst, unsigned short* __restrict__ Vdst,
    float qscale)
{
    __shared__ __align__(16) short sA[FM*72];
    __shared__ __align__(16) short sT[FM*72];
    int bid = blockIdx.x;
    int wt = bid & 7, h = (bid>>3)&127, b = bid>>10;
    int tid = threadIdx.x;
    int w0 = wt << 6;

    // ---- stage A: rows hr=0..2 (h-1..h+1), wi=0..65 (w0-1..w0+64), 64 c ----
    if (tid < 192){
        int c = tid & 63, hr = tid >> 6;
        int hh = h - 1 + hr;
        int hc = min(max(hh, 0), 127);
        const float* xrow = x + ((size_t)(b*64 + c)*128 + hc)*512;
        short* dst = sA + (hr*66)*72 + c;
        {   // wi = 0 (w0-1), clamped (value ignored if invalid)
            int wc = max(w0 - 1, 0);
            dst[0] = (short)f2bf(xrow[wc]);
        }
        #pragma unroll
        for (int j=0; j<16; j++){
            float4 v = *(const float4*)(xrow + w0 + j*4);
            int wi = 1 + j*4;
            dst[(wi+0)*72] = (short)f2bf(v.x);
            dst[(wi+1)*72] = (short)f2bf(v.y);
            dst[(wi+2)*72] = (short)f2bf(v.z);
            dst[(wi+3)*72] = (short)f2bf(v.w);
        }
        {   // wi = 65 (w0+64), clamped
            int wc = min(w0 + 64, 511);
            dst[65*72] = (short)f2bf(xrow[wc]);
        }
    }
    __syncthreads();

    int wv = tid>>6, lane = tid&63, quad = lane>>4, l16 = lane&15;
    int cg = tid & 15, wl = tid >> 4;
    int c0 = cg*4;
    const f32x4 z4 = {0.f,0.f,0.f,0.f};

    for (int set=0; set<2; set++){
        const float* wset = set ? w2 : w1;
        const float* bset = set ? b2 : b1;
        // W fragments from global (L2-hot), bias per nt
        short8 bw0[4], bw1[4]; float bias[4];
        #pragma unroll
        for (int nt=0; nt<4; nt++){
            const float* wrow = wset + (nt*16 + l16)*64 + quad*8;
            float4 wa = *(const float4*)(wrow);
            float4 wb = *(const float4*)(wrow + 4);
            float4 wc = *(const float4*)(wrow + 32);
            float4 we = *(const float4*)(wrow + 36);
            bw0[nt][0]=(short)f2bf(wa.x); bw0[nt][1]=(short)f2bf(wa.y); bw0[nt][2]=(short)f2bf(wa.z); bw0[nt][3]=(short)f2bf(wa.w);
            bw0[nt][4]=(short)f2bf(wb.x); bw0[nt][5]=(short)f2bf(wb.y); bw0[nt][6]=(short)f2bf(wb.z); bw0[nt][7]=(short)f2bf(wb.w);
            bw1[nt][0]=(short)f2bf(wc.x); bw1[nt][1]=(short)f2bf(wc.y); bw1[nt][2]=(short)f2bf(wc.z); bw1[nt][3]=(short)f2bf(wc.w);
            bw1[nt][4]=(short)f2bf(we.x); bw1[nt][5]=(short)f2bf(we.y); bw1[nt][6]=(short)f2bf(we.z); bw1[nt][7]=(short)f2bf(we.w);
            bias[nt] = bset[nt*16 + l16];
        }
        // conv1x1 MFMA: m-tiles striped across waves (0..12)
        for (int mt = wv; mt < 13; mt += 4){
            short8 a0 = *(const short8*)(sA + (mt*16 + l16)*72 + quad*8);
            short8 a1 = *(const short8*)(sA + (mt*16 + l16)*72 + 32 + quad*8);
            f32x4 acc[4];
            #pragma unroll
            for (int nt=0; nt<4; nt++){
                acc[nt] = __builtin_amdgcn_mfma_f32_16x16x32_bf16(a0, bw0[nt], z4, 0,0,0);
                acc[nt] = __builtin_amdgcn_mfma_f32_16x16x32_bf16(a1, bw1[nt], acc[nt], 0,0,0);
            }
            #pragma unroll
            for (int nt=0; nt<4; nt++){
                #pragma unroll
                for (int r=0;r<4;r++)
                    sT[(mt*16 + quad*4 + r)*72 + nt*16 + l16] = (short)f2bf(acc[nt][r] + bias[nt]);
            }
        }
        __syncthreads();
        // dwconv 3x3 from sT, coordinate-validity = zero padding
        const float* wdk = set ? wd2 : wd1;
        const float* bdk = set ? bd2 : bd1;
        float acc[4][4];   // [ch][w]
        #pragma unroll
        for (int ch=0; ch<4; ch++){
            float bv = bdk[c0+ch];
            #pragma unroll
            for (int i=0;i<4;i++) acc[ch][i] = bv;
        }
        #pragma unroll
        for (int dh=-1; dh<=1; dh++){
            int hh = h + dh;
            if (hh < 0 || hh > 127) continue;
            const short* Trow = sT + ((dh+1)*66)*72 + c0;
            float win[6][4];
            #pragma unroll
            for (int j=0;j<6;j++){
                int wimg = w0 - 1 + wl*4 + j;
                if (wimg >= 0 && wimg < 512){
                    uint2 v = *(const uint2*)(Trow + (wl*4 + j)*72);
                    win[j][0] = __uint_as_float(v.x<<16);
                    win[j][1] = __uint_as_float(v.x & 0xffff0000u);
                    win[j][2] = __uint_as_float(v.y<<16);
                    win[j][3] = __uint_as_float(v.y & 0xffff0000u);
                } else {
                    win[j][0]=0.f; win[j][1]=0.f; win[j][2]=0.f; win[j][3]=0.f;
                }
            }
            #pragma unroll
            for (int ch=0; ch<4; ch++){
                float k0 = wdk[(c0+ch)*9 + (dh+1)*3];
                float k1 = wdk[(c0+ch)*9 + (dh+1)*3 + 1];
                float k2 = wdk[(c0+ch)*9 + (dh+1)*3 + 2];
                #pragma unroll
                for (int i=0;i<4;i++)
                    acc[ch][i] += k0*win[i][ch] + k1*win[i+1][ch] + k2*win[i+2][ch];
            }
        }
        if (set == 0){
            int base = (b*128 + h)*512;
            #pragma unroll
            for (int i=0;i<4;i++){
                uint2 v;
                v.x = pk_rtne(acc[1][i]*qscale, acc[0][i]*qscale);
                v.y = pk_rtne(acc[3][i]*qscale, acc[2][i]*qscale);
                *(uint2*)(Qdst + ((size_t)(base + w0 + wl*4 + i))*64 + c0) = v;
            }
            __syncthreads();   // sT reads done before set-1 MFMA overwrites
        } else {
            #pragma unroll
            for (int ch=0; ch<4; ch++){
                uint2 v;
                v.x = pk_rtne(acc[ch][1], acc[ch][0]);
                v.y = pk_rtne(acc[ch][3], acc[ch][2]);
                *(uint2*)(Vdst + (((size_t)(b*64 + c0 + ch))<<16) + h*512 + w0 + wl*4) = v;
            }
        }
    }
}

// ---------------- flash attention + fused output conv1x1, atomic add into out ----------------
// R4/R6-proven structure: Q-tile 64, S^T orientation, sP aliases sQ, XCD swizzle.
#define PQ 72
#define PK 72
#define PV 72
#define PP 72
#define PW 72
#define PFA 72
#define POT 17
#define OFF_Q   0        // sQ / sP / sFA alias: 64*72*2 = 9216
#define OFF_K   9216     // 9216 ; sOT aliases sK+sV (4*64*17*4 = 17408 <= 18432)
#define OFF_V   18432    // 9216
#define OFF_W3  27648    // 9216
#define LDS_TOT 36864

__global__ __launch_bounds__(256) void flash_k(
    const unsigned short* __restrict__ Ql, const unsigned short* __restrict__ Qr,
    const unsigned short* __restrict__ Vl, const unsigned short* __restrict__ Vr,
    const float* __restrict__ lw3, const float* __restrict__ lb3,
    const float* __restrict__ rw3, const float* __restrict__ rb3,
    float* __restrict__ out)
{
    __shared__ __align__(16) char smem[LDS_TOT];
    short* sQ  = (short*)(smem + OFF_Q);
    short* sK  = (short*)(smem + OFF_K);
    short* sV  = (short*)(smem + OFF_V);
    short* sP  = (short*)(smem + OFF_Q);   // alias over sQ
    short* sW  = (short*)(smem + OFF_W3);
    short* sFA = (short*)(smem + OFF_Q);   // alias over sQ (epilogue)
    float* sOT = (float*)(smem + OFF_K);   // alias over sK+sV (epilogue)

    // XCD-aware swizzle: 8 q-tiles of one (dir,b,h) share bid%8 within a 64-block window.
    int bid = blockIdx.x;
    int g  = ((bid >> 6) << 3) | (bid & 7);   // 0..511 = dir*256 + b*128 + h
    int qt = (bid >> 3) & 7;
    int h = g & 127, b = (g >> 7) & 1, dir = g >> 8;
    const unsigned short *Qg, *Kg, *Vg; const float *w3, *b3;
    if (dir==0){ Qg = Ql; Kg = Qr; Vg = Vr; w3 = lw3; b3 = lb3; }
    else       { Qg = Qr; Kg = Ql; Vg = Vl; w3 = rw3; b3 = rb3; }

    int tid = threadIdx.x;
    int wv = tid>>6, lane = tid&63, quad = lane>>4, l16 = lane&15;
    int bh = b*128 + h;

    {   // stage Q tile (64 q x 64 c) and W3 [o][c]
        const uint4* src = (const uint4*)(Qg + ((size_t)bh*512 + qt*64)*64);
        #pragma unroll
        for (int it=0; it<2; it++){
            int idx = it*256 + tid;
            int row = idx>>3, piece = idx&7;
            *(uint4*)(sQ + row*PQ + piece*8) = src[idx];
        }
        #pragma unroll
        for (int it=0; it<16; it++){
            int idx = it*256 + tid;
            int o = idx>>6, cc = idx&63;
            sW[o*PW + cc] = (short)f2bf(w3[idx]);
        }
    }
    __syncthreads();

    short8 aq0 = *(const short8*)(sQ + (wv*16 + l16)*PQ + quad*8);
    short8 aq1 = *(const short8*)(sQ + (wv*16 + l16)*PQ + 32 + quad*8);

    const f32x4 z4 = {0.f,0.f,0.f,0.f};
    f32x4 oacc[4];
    #pragma unroll
    for (int ct=0; ct<4; ct++) oacc[ct] = z4;
    float lps = 0.f;

    const uint4* Ksrc = (const uint4*)(Kg + (size_t)bh*512*64);
    const unsigned short* Vbase = Vg + ((size_t)(b*64)*128 + h)*512;
    short* sPw = sP + wv*16*PP;

    for (int kt=0; kt<8; kt++){
        #pragma unroll
        for (int it=0; it<2; it++){
            int idx = it*256 + tid;
            int row = idx>>3, piece = idx&7;
            *(uint4*)(sK + row*PK + piece*8) = Ksrc[(size_t)(kt*64 + row)*8 + piece];
            uint4 vv = *(const uint4*)(Vbase + (size_t)row*65536 + kt*64 + piece*8);
            *(uint4*)(sV + row*PV + piece*8) = vv;
        }
        __syncthreads();
        // S^T = K Q^T: D[row=key=nt*16+quad*4+r][col=q=l16]
        #pragma unroll
        for (int nt=0; nt<4; nt++){
            short8 bk0 = *(const short8*)(sK + (nt*16 + l16)*PK + quad*8);
            short8 bk1 = *(const short8*)(sK + (nt*16 + l16)*PK + 32 + quad*8);
            f32x4 s = __builtin_amdgcn_mfma_f32_16x16x32_bf16(bk0, aq0, z4, 0,0,0);
            s       = __builtin_amdgcn_mfma_f32_16x16x32_bf16(bk1, aq1, s, 0,0,0);
            float p0 = __builtin_amdgcn_exp2f(s[0]);
            float p1 = __builtin_amdgcn_exp2f(s[1]);
            float p2 = __builtin_amdgcn_exp2f(s[2]);
            float p3 = __builtin_amdgcn_exp2f(s[3]);
            lps += (p0+p1) + (p2+p3);
            unsigned lo = __builtin_amdgcn_perm(__float_as_uint(p1), __float_as_uint(p0), 0x07060302);
            unsigned hi = __builtin_amdgcn_perm(__float_as_uint(p3), __float_as_uint(p2), 0x07060302);
            uint2 pv; pv.x = lo; pv.y = hi;
            *(uint2*)(sPw + l16*PP + nt*16 + quad*4) = pv;
        }
        // same-wave LDS write->read: no barrier needed (per-wave region)
        short8 ap0 = *(const short8*)(sPw + l16*PP + quad*8);
        short8 ap1 = *(const short8*)(sPw + l16*PP + 32 + quad*8);
        #pragma unroll
        for (int ct=0; ct<4; ct++){
            short8 bv0 = *(const short8*)(sV + (ct*16 + l16)*PV + quad*8);
            short8 bv1 = *(const short8*)(sV + (ct*16 + l16)*PV + 32 + quad*8);
            oacc[ct] = __builtin_amdgcn_mfma_f32_16x16x32_bf16(ap0, bv0, oacc[ct], 0,0,0);
            oacc[ct] = __builtin_amdgcn_mfma_f32_16x16x32_bf16(ap1, bv1, oacc[ct], 0,0,0);
        }
        __syncthreads();
    }

    // l(q=l16) = sum over the 4 key-quads
    float l = lps;
    l += __shfl_xor(l, 16);
    l += __shfl_xor(l, 32);
    float inv[4];
    #pragma unroll
    for (int r=0;r<4;r++) inv[r] = 1.0f / __shfl(l, quad*4 + r);

    // epilogue: F -> LDS (A layout), conv1x1 via MFMA with sW, bias, transpose, atomic add
    short* sFw = sFA + wv*16*PFA;
    #pragma unroll
    for (int ct=0; ct<4; ct++){
        #pragma unroll
        for (int r=0;r<4;r++)
            sFw[(quad*4+r)*PFA + ct*16 + l16] = (short)f2bf(oacc[ct][r]*inv[r]);
    }
    short8 af0 = *(const short8*)(sFw + l16*PFA + quad*8);
    short8 af1 = *(const short8*)(sFw + l16*PFA + 32 + quad*8);
    f32x4 d2[4];
    #pragma unroll
    for (int ot=0; ot<4; ot++){
        short8 bw0 = *(const short8*)(sW + (ot*16 + l16)*PW + quad*8);
        short8 bw1 = *(const short8*)(sW + (ot*16 + l16)*PW + 32 + quad*8);
        d2[ot] = __builtin_amdgcn_mfma_f32_16x16x32_bf16(af0, bw0, z4, 0,0,0);
        d2[ot] = __builtin_amdgcn_mfma_f32_16x16x32_bf16(af1, bw1, d2[ot], 0,0,0);
        float bias = b3[ot*16 + l16];
        #pragma unroll
        for (int r=0;r<4;r++) d2[ot][r] += bias;
    }
    __syncthreads();  // sK/sV definitively dead for ALL waves before sOT writes
    float* sOw = sOT + wv*(64*POT);
    #pragma unroll
    for (int ot=0; ot<4; ot++){
        #pragma unroll
        for (int r=0;r<4;r++)
            sOw[(ot*16 + l16)*POT + quad*4 + r] = d2[ot][r];
    }
    int wbase = qt*64 + wv*16;
    #pragma unroll
    for (int it=0; it<16; it++){
        int o = it*4 + quad;
        float val = sOw[o*POT + l16];
        unsafeAtomicAdd(out + ((size_t)(b*64 + o)*128 + h)*512 + wbase + l16, val);
    }
}

extern "C" void kernel_launch(void* const* d_in, const int* in_sizes, int n_in,
                              void* d_out, int out_size, void* d_ws, size_t ws_size,
                              hipStream_t stream)
{
    const float* xl = (const float*)d_in[0];
    const float* xr = (const float*)d_in[1];
    const float* lp1_w1 = (const float*)d_in[2];
    const float* lp1_b1 = (const float*)d_in[3];
    const float* lp1_wd = (const float*)d_in[4];
    const float* lp1_bd = (const float*)d_in[5];
    const float* rp1_w1 = (const float*)d_in[6];
    const float* rp1_b1 = (const float*)d_in[7];
    const float* rp1_wd = (const float*)d_in[8];
    const float* rp1_bd = (const float*)d_in[9];
    const float* lp2_w1 = (const float*)d_in[10];
    const float* lp2_b1 = (const float*)d_in[11];
    const float* lp2_wd = (const float*)d_in[12];
    const float* lp2_bd = (const float*)d_in[13];
    const float* rp2_w1 = (const float*)d_in[14];
    const float* rp2_b1 = (const float*)d_in[15];
    const float* rp2_wd = (const float*)d_in[16];
    const float* rp2_bd = (const float*)d_in[17];
    const float* lp3_w  = (const float*)d_in[18];
    const float* lp3_b  = (const float*)d_in[19];
    const float* rp3_w  = (const float*)d_in[20];
    const float* rp3_b  = (const float*)d_in[21];
    float* out = (float*)d_out;

    // 4 slots of 16 MiB: Ql | Qr | Vl | Vr (= 64 MiB). No T, no Xt.
    const size_t S = 16777216;
    char* ws = (char*)d_ws;
    unsigned short* Ql  = (unsigned short*)(ws);
    unsigned short* Qr  = (unsigned short*)(ws + 1*S);
    unsigned short* Vl  = (unsigned short*)(ws + 2*S);
    unsigned short* Vr  = (unsigned short*)(ws + 3*S);

    init_out_k<<<8192, 256, 0, stream>>>(xl, xr, out, 2097152);

    fused_proj_k<<<2048, 256, 0, stream>>>(xl,
        lp1_w1, lp1_b1, lp1_wd, lp1_bd,
        lp2_w1, lp2_b1, lp2_wd, lp2_bd,
        Ql, Vl, QSCALE);

    fused_proj_k<<<2048, 256, 0, stream>>>(xr,
        rp1_w1, rp1_b1, rp1_wd, rp1_bd,
        rp2_w1, rp2_b1, rp2_wd, rp2_bd,
        Qr, Vr, 1.0f);

    flash_k<<<4096, 256, 0, stream>>>(Ql, Qr, Vl, Vr, lp3_w, lp3_b, rp3_w, rp3_b, out);
}

// Round 8
// 326.944 us; speedup vs baseline: 1.1070x; 1.1070x over previous
//
#include <hip/hip_runtime.h>
#include <hip/hip_bf16.h>

typedef __attribute__((ext_vector_type(8))) short short8;
typedef __attribute__((ext_vector_type(4))) float f32x4;

// SCALE * log2(e), folded into Ql at store time; flash uses exp2 directly.
#define QSCALE 0.18033688011112042f

__device__ __forceinline__ unsigned short f2bf(float f){
    unsigned u = __float_as_uint(f);
    unsigned r = (u + 0x7fffu + ((u>>16)&1u))>>16;
    return (unsigned short)r;
}
__device__ __forceinline__ unsigned pk_rtne(float hi, float lo){
    return (((unsigned)f2bf(hi))<<16) | (unsigned)f2bf(lo);
}

// ---------------- fused: out = xl + xr, XtL/XtR = transpose([c,px] -> [px,c]) bf16 ----------------
// grid: 2 b * 1024 strips of 64 px; LDS 64c x 64px fp32 tile (pad 65), bank-clean both ways.
__global__ __launch_bounds__(256) void prep_k(const float* __restrict__ xl,
                                              const float* __restrict__ xr,
                                              float* __restrict__ out,
                                              unsigned short* __restrict__ XtL,
                                              unsigned short* __restrict__ XtR){
    __shared__ float ft[64*65];
    int bid = blockIdx.x;
    int strip = bid & 1023, b = bid >> 10;
    int px0 = strip << 6;
    int tid = threadIdx.x;
    float4 vrs[4];
    #pragma unroll
    for (int it=0; it<4; it++){
        int lin = it*256 + tid;
        int c = lin >> 4, piece = lin & 15;
        size_t off = (((size_t)(b*64 + c))<<16) + px0 + piece*4;
        float4 va = *(const float4*)(xl + off);
        float4 vb = *(const float4*)(xr + off);
        vrs[it] = vb;
        float4 vo; vo.x=va.x+vb.x; vo.y=va.y+vb.y; vo.z=va.z+vb.z; vo.w=va.w+vb.w;
        *(float4*)(out + off) = vo;
        float* d = ft + c*65 + piece*4;
        d[0]=va.x; d[1]=va.y; d[2]=va.z; d[3]=va.w;
    }
    __syncthreads();
    #pragma unroll
    for (int it=0; it<2; it++){
        int lin = it*256 + tid;
        int pxl = lin >> 3, cb = lin & 7;
        unsigned r[4];
        #pragma unroll
        for (int j=0;j<4;j++){
            unsigned lo = f2bf(ft[(cb*8 + 2*j  )*65 + pxl]);
            unsigned hi = f2bf(ft[(cb*8 + 2*j+1)*65 + pxl]);
            r[j] = lo | (hi<<16);
        }
        uint4 v; v.x=r[0]; v.y=r[1]; v.z=r[2]; v.w=r[3];
        *(uint4*)(XtL + ((size_t)(b<<16) + px0 + pxl)*64 + cb*8) = v;
    }
    __syncthreads();
    #pragma unroll
    for (int it=0; it<4; it++){
        int lin = it*256 + tid;
        int c = lin >> 4, piece = lin & 15;
        float4 vb = vrs[it];
        float* d = ft + c*65 + piece*4;
        d[0]=vb.x; d[1]=vb.y; d[2]=vb.z; d[3]=vb.w;
    }
    __syncthreads();
    #pragma unroll
    for (int it=0; it<2; it++){
        int lin = it*256 + tid;
        int pxl = lin >> 3, cb = lin & 7;
        unsigned r[4];
        #pragma unroll
        for (int j=0;j<4;j++){
            unsigned lo = f2bf(ft[(cb*8 + 2*j  )*65 + pxl]);
            unsigned hi = f2bf(ft[(cb*8 + 2*j+1)*65 + pxl]);
            r[j] = lo | (hi<<16);
        }
        uint4 v; v.x=r[0]; v.y=r[1]; v.z=r[2]; v.w=r[3];
        *(uint4*)(XtR + ((size_t)(b<<16) + px0 + pxl)*64 + cb*8) = v;
    }
}

// ---------------- dual conv1x1 via MFMA from Xt [px,64] bf16 -> T1/T2 [px,64], BOTH sides ----------------
// grid 1024 blocks (side = bid>>9, 256 px each), 256 threads (4 waves).
__global__ __launch_bounds__(256) void gemm_k(const unsigned short* __restrict__ XtL,
                                              const unsigned short* __restrict__ XtR,
                                              const float* __restrict__ wAL, const float* __restrict__ bAL,
                                              const float* __restrict__ wBL, const float* __restrict__ bBL,
                                              const float* __restrict__ wAR, const float* __restrict__ bAR,
                                              const float* __restrict__ wBR, const float* __restrict__ bBR,
                                              unsigned short* __restrict__ T1L, unsigned short* __restrict__ T2L,
                                              unsigned short* __restrict__ T1R, unsigned short* __restrict__ T2R){
    __shared__ __align__(16) short sA[256*72];
    __shared__ __align__(16) short sB[128*72];
    __shared__ float sbias[128];
    int tid = threadIdx.x;
    int side = blockIdx.x >> 9;
    int px0 = (blockIdx.x & 511) << 8;
    const unsigned short* Xt = side ? XtR : XtL;
    const float* wA = side ? wAR : wAL;  const float* bA = side ? bAR : bAL;
    const float* wB = side ? wBR : wBL;  const float* bB = side ? bBR : bBL;
    unsigned short* T1 = side ? T1R : T1L;
    unsigned short* T2 = side ? T2R : T2L;
    {
        const uint4* src = (const uint4*)(Xt + (size_t)px0*64);
        #pragma unroll
        for (int it=0; it<8; it++){
            int lin = it*256 + tid;
            int row = lin >> 3, piece = lin & 7;
            *(uint4*)(sA + row*72 + piece*8) = src[lin];
        }
        #pragma unroll
        for (int it=0; it<32; it++){
            int lin = it*256 + tid;
            int o = lin >> 6, cc = lin & 63;
            float wv = (o < 64) ? wA[o*64 + cc] : wB[(o-64)*64 + cc];
            sB[o*72 + cc] = (short)f2bf(wv);
        }
        if (tid < 128) sbias[tid] = (tid < 64) ? bA[tid] : bB[tid-64];
    }
    __syncthreads();
    int wv = tid>>6, lane = tid&63, quad = lane>>4, l16 = lane&15;
    int m0 = wv*64;
    short8 a0[4], a1[4];
    #pragma unroll
    for (int mt=0; mt<4; mt++){
        a0[mt] = *(const short8*)(sA + (m0 + mt*16 + l16)*72 + quad*8);
        a1[mt] = *(const short8*)(sA + (m0 + mt*16 + l16)*72 + 32 + quad*8);
    }
    const f32x4 z4 = {0.f,0.f,0.f,0.f};
    #pragma unroll
    for (int set=0; set<2; set++){
        unsigned short* T = set ? T2 : T1;
        short8 bB0[4], bB1[4];
        #pragma unroll
        for (int nt=0; nt<4; nt++){
            bB0[nt] = *(const short8*)(sB + (set*64 + nt*16 + l16)*72 + quad*8);
            bB1[nt] = *(const short8*)(sB + (set*64 + nt*16 + l16)*72 + 32 + quad*8);
        }
        f32x4 acc[4][4];
        #pragma unroll
        for (int mt=0; mt<4; mt++)
            #pragma unroll
            for (int nt=0; nt<4; nt++){
                acc[mt][nt] = __builtin_amdgcn_mfma_f32_16x16x32_bf16(a0[mt], bB0[nt], z4, 0,0,0);
                acc[mt][nt] = __builtin_amdgcn_mfma_f32_16x16x32_bf16(a1[mt], bB1[nt], acc[mt][nt], 0,0,0);
            }
        #pragma unroll
        for (int nt=0; nt<4; nt++){
            float bias = sbias[set*64 + nt*16 + l16];
            #pragma unroll
            for (int mt=0; mt<4; mt++){
                #pragma unroll
                for (int r=0;r<4;r++){
                    int pxr = px0 + m0 + mt*16 + quad*4 + r;
                    T[(size_t)pxr*64 + nt*16 + l16] = f2bf(acc[mt][nt][r] + bias);
                }
            }
        }
    }
}

// ---------------- dual depthwise 3x3: T1->Q (scaled, [b,hw,c]), T2->V ([b,c,hw]) ----------------
__device__ __forceinline__ void dw_tile(const unsigned short* __restrict__ Tb,
                                        const float* __restrict__ wd,
                                        const float* __restrict__ bd,
                                        int c0, int w0, int h, float acc[4][4]){
    #pragma unroll
    for (int ch=0; ch<4; ch++){
        float bv = bd[c0+ch];
        #pragma unroll
        for (int i=0;i<4;i++) acc[ch][i] = bv;
    }
    #pragma unroll
    for (int dh=-1; dh<=1; dh++){
        int hh = h + dh;
        if (hh < 0 || hh > 127) continue;
        const unsigned short* Tr = Tb + ((size_t)(hh*512))*64 + c0;
        float win[6][4];
        #pragma unroll
        for (int j=0;j<6;j++){
            int ww = w0 - 1 + j;
            if (ww >= 0 && ww < 512){
                uint2 v = *(const uint2*)(Tr + (size_t)ww*64);
                win[j][0] = __uint_as_float(v.x<<16);
                win[j][1] = __uint_as_float(v.x & 0xffff0000u);
                win[j][2] = __uint_as_float(v.y<<16);
                win[j][3] = __uint_as_float(v.y & 0xffff0000u);
            } else {
                win[j][0]=0.f; win[j][1]=0.f; win[j][2]=0.f; win[j][3]=0.f;
            }
        }
        #pragma unroll
        for (int ch=0; ch<4; ch++){
            float k0 = wd[(c0+ch)*9 + (dh+1)*3];
            float k1 = wd[(c0+ch)*9 + (dh+1)*3 + 1];
            float k2 = wd[(c0+ch)*9 + (dh+1)*3 + 2];
            #pragma unroll
            for (int i=0;i<4;i++)
                acc[ch][i] += k0*win[i][ch] + k1*win[i+1][ch] + k2*win[i+2][ch];
        }
    }
}

__global__ __launch_bounds__(256) void dwconv_k(const unsigned short* __restrict__ T1,
                                                const unsigned short* __restrict__ T2,
                                                const float* __restrict__ wd1,
                                                const float* __restrict__ bd1,
                                                const float* __restrict__ wd2,
                                                const float* __restrict__ bd2,
                                                unsigned short* __restrict__ Qdst,
                                                unsigned short* __restrict__ Vdst,
                                                float qscale){
    int bid = blockIdx.x;
    int wt = bid & 7, h = (bid>>3)&127, b = bid>>10;
    int tid = threadIdx.x;
    int cg = tid & 15, wl = tid >> 4;
    int c0 = cg*4;
    int w0 = wt*64 + wl*4;
    float acc[4][4];   // [ch][w]
    dw_tile(T1 + ((size_t)b<<22), wd1, bd1, c0, w0, h, acc);
    {
        int base = (b*128 + h)*512;
        #pragma unroll
        for (int i=0;i<4;i++){
            uint2 v;
            v.x = pk_rtne(acc[1][i]*qscale, acc[0][i]*qscale);
            v.y = pk_rtne(acc[3][i]*qscale, acc[2][i]*qscale);
            *(uint2*)(Qdst + ((size_t)(base + w0 + i))*64 + c0) = v;
        }
    }
    dw_tile(T2 + ((size_t)b<<22), wd2, bd2, c0, w0, h, acc);
    {
        #pragma unroll
        for (int ch=0; ch<4; ch++){
            uint2 v;
            v.x = pk_rtne(acc[ch][1], acc[ch][0]);
            v.y = pk_rtne(acc[ch][3], acc[ch][2]);
            *(uint2*)(Vdst + (((size_t)(b*64 + c0 + ch))<<16) + h*512 + w0) = v;
        }
    }
}

// ---------------- flash attention + fused output conv1x1, atomic add into out ----------------
// Q-tile 128, 2 q-subtiles/wave (R5-proven math, WITHOUT prefetch regs / min-waves clause).
// K/V fragments and staging serve 2x q-work -> LDS traffic per work halved vs Q-tile 64.
#define PQ 72
#define PK 72
#define PV 72
#define PP 72
#define PFA 72
#define POT 17
#define OFF_Q   0        // 128*72*2 = 18432 ; sP/sFA alias
#define OFF_K   18432    // 64*72*2 = 9216 ; sOT aliases sK+sV (4*64*17*4 = 17408 <= 18432)
#define OFF_V   27648    // 9216
#define LDS_TOT 36864

__global__ __launch_bounds__(256) void flash_k(
    const unsigned short* __restrict__ Ql, const unsigned short* __restrict__ Qr,
    const unsigned short* __restrict__ Vl, const unsigned short* __restrict__ Vr,
    const float* __restrict__ lw3, const float* __restrict__ lb3,
    const float* __restrict__ rw3, const float* __restrict__ rb3,
    float* __restrict__ out)
{
    __shared__ __align__(16) char smem[LDS_TOT];
    short* sQ  = (short*)(smem + OFF_Q);
    short* sK  = (short*)(smem + OFF_K);
    short* sV  = (short*)(smem + OFF_V);
    short* sP  = (short*)(smem + OFF_Q);   // alias over sQ (per-wave 32-row slices)
    short* sFA = (short*)(smem + OFF_Q);   // alias over sQ (epilogue)
    float* sOT = (float*)(smem + OFF_K);   // alias over sK+sV (epilogue)

    // XCD swizzle: 4 q-tiles of one (dir,b,h) share bid%8 within a 32-block window.
    int bid = blockIdx.x;
    int g  = ((bid >> 5) << 3) | (bid & 7);   // 0..511 = dir*256 + b*128 + h
    int qt = (bid >> 3) & 3;
    int h = g & 127, b = (g >> 7) & 1, dir = g >> 8;
    const unsigned short *Qg, *Kg, *Vg; const float *w3, *b3;
    if (dir==0){ Qg = Ql; Kg = Qr; Vg = Vr; w3 = lw3; b3 = lb3; }
    else       { Qg = Qr; Kg = Ql; Vg = Vl; w3 = rw3; b3 = rb3; }

    int tid = threadIdx.x;
    int wv = tid>>6, lane = tid&63, quad = lane>>4, l16 = lane&15;
    int bh = b*128 + h;

    {   // stage Q tile (128 q x 64 c)
        const uint4* src = (const uint4*)(Qg + ((size_t)bh*512 + qt*128)*64);
        #pragma unroll
        for (int it=0; it<4; it++){
            int idx = it*256 + tid;
            int row = idx>>3, piece = idx&7;
            *(uint4*)(sQ + row*PQ + piece*8) = src[idx];
        }
    }
    __syncthreads();

    short8 aq0[2], aq1[2];
    #pragma unroll
    for (int s=0; s<2; s++){
        aq0[s] = *(const short8*)(sQ + (wv*32 + s*16 + l16)*PQ + quad*8);
        aq1[s] = *(const short8*)(sQ + (wv*32 + s*16 + l16)*PQ + 32 + quad*8);
    }

    const f32x4 z4 = {0.f,0.f,0.f,0.f};
    f32x4 oacc[2][4];
    #pragma unroll
    for (int s=0; s<2; s++)
        #pragma unroll
        for (int ct=0; ct<4; ct++) oacc[s][ct] = z4;
    float lps[2] = {0.f, 0.f};

    const uint4* Ksrc = (const uint4*)(Kg + (size_t)bh*512*64);
    const unsigned short* Vbase = Vg + ((size_t)(b*64)*128 + h)*512;

    for (int kt=0; kt<8; kt++){
        #pragma unroll
        for (int it=0; it<2; it++){
            int idx = it*256 + tid;
            int row = idx>>3, piece = idx&7;
            *(uint4*)(sK + row*PK + piece*8) = Ksrc[(size_t)(kt*64 + row)*8 + piece];
            uint4 vv = *(const uint4*)(Vbase + (size_t)row*65536 + kt*64 + piece*8);
            *(uint4*)(sV + row*PV + piece*8) = vv;
        }
        __syncthreads();
        // S^T = K Q^T per q-subtile: D[row=key=nt*16+quad*4+r][col=q=l16]
        #pragma unroll
        for (int nt=0; nt<4; nt++){
            short8 bk0 = *(const short8*)(sK + (nt*16 + l16)*PK + quad*8);
            short8 bk1 = *(const short8*)(sK + (nt*16 + l16)*PK + 32 + quad*8);
            #pragma unroll
            for (int s=0; s<2; s++){
                f32x4 sv = __builtin_amdgcn_mfma_f32_16x16x32_bf16(bk0, aq0[s], z4, 0,0,0);
                sv       = __builtin_amdgcn_mfma_f32_16x16x32_bf16(bk1, aq1[s], sv, 0,0,0);
                float p0 = __builtin_amdgcn_exp2f(sv[0]);
                float p1 = __builtin_amdgcn_exp2f(sv[1]);
                float p2 = __builtin_amdgcn_exp2f(sv[2]);
                float p3 = __builtin_amdgcn_exp2f(sv[3]);
                lps[s] += (p0+p1) + (p2+p3);
                unsigned lo = __builtin_amdgcn_perm(__float_as_uint(p1), __float_as_uint(p0), 0x07060302);
                unsigned hi = __builtin_amdgcn_perm(__float_as_uint(p3), __float_as_uint(p2), 0x07060302);
                uint2 pv; pv.x = lo; pv.y = hi;
                *(uint2*)(sP + (wv*32 + s*16 + l16)*PP + nt*16 + quad*4) = pv;
            }
        }
        // same-wave LDS write->read: no barrier needed (per-wave region)
        short8 ap0[2], ap1[2];
        #pragma unroll
        for (int s=0; s<2; s++){
            ap0[s] = *(const short8*)(sP + (wv*32 + s*16 + l16)*PP + quad*8);
            ap1[s] = *(const short8*)(sP + (wv*32 + s*16 + l16)*PP + 32 + quad*8);
        }
        #pragma unroll
        for (int ct=0; ct<4; ct++){
            short8 bv0 = *(const short8*)(sV + (ct*16 + l16)*PV + quad*8);
            short8 bv1 = *(const short8*)(sV + (ct*16 + l16)*PV + 32 + quad*8);
            #pragma unroll
            for (int s=0; s<2; s++){
                oacc[s][ct] = __builtin_amdgcn_mfma_f32_16x16x32_bf16(ap0[s], bv0, oacc[s][ct], 0,0,0);
                oacc[s][ct] = __builtin_amdgcn_mfma_f32_16x16x32_bf16(ap1[s], bv1, oacc[s][ct], 0,0,0);
            }
        }
        __syncthreads();
    }

    // l(q) reduction
    float inv[2][4];
    #pragma unroll
    for (int s=0; s<2; s++){
        float l = lps[s];
        l += __shfl_xor(l, 16);
        l += __shfl_xor(l, 32);
        #pragma unroll
        for (int r=0;r<4;r++) inv[s][r] = 1.0f / __shfl(l, quad*4 + r);
    }

    // epilogue: F -> LDS (A layout), conv1x1 MFMA with W3 frags from global, bias,
    // LDS transpose, atomic add. Last K-loop barrier guarantees sK/sV/sQ dead.
    #pragma unroll
    for (int s=0; s<2; s++){
        short* sFw = sFA + (wv*32 + s*16)*PFA;
        #pragma unroll
        for (int ct=0; ct<4; ct++){
            #pragma unroll
            for (int r=0;r<4;r++)
                sFw[(quad*4+r)*PFA + ct*16 + l16] = (short)f2bf(oacc[s][ct][r]*inv[s][r]);
        }
    }
    short8 af0[2], af1[2];
    #pragma unroll
    for (int s=0; s<2; s++){
        af0[s] = *(const short8*)(sFA + (wv*32 + s*16 + l16)*PFA + quad*8);
        af1[s] = *(const short8*)(sFA + (wv*32 + s*16 + l16)*PFA + 32 + quad*8);
    }
    f32x4 d2[2][4];
    #pragma unroll
    for (int ot=0; ot<4; ot++){
        const float* wrow = w3 + (ot*16 + l16)*64 + quad*8;
        float4 wa = *(const float4*)(wrow);
        float4 wb = *(const float4*)(wrow + 4);
        float4 wc = *(const float4*)(wrow + 32);
        float4 wd = *(const float4*)(wrow + 36);
        short8 bw0, bw1;
        bw0[0]=(short)f2bf(wa.x); bw0[1]=(short)f2bf(wa.y); bw0[2]=(short)f2bf(wa.z); bw0[3]=(short)f2bf(wa.w);
        bw0[4]=(short)f2bf(wb.x); bw0[5]=(short)f2bf(wb.y); bw0[6]=(short)f2bf(wb.z); bw0[7]=(short)f2bf(wb.w);
        bw1[0]=(short)f2bf(wc.x); bw1[1]=(short)f2bf(wc.y); bw1[2]=(short)f2bf(wc.z); bw1[3]=(short)f2bf(wc.w);
        bw1[4]=(short)f2bf(wd.x); bw1[5]=(short)f2bf(wd.y); bw1[6]=(short)f2bf(wd.z); bw1[7]=(short)f2bf(wd.w);
        float bias = b3[ot*16 + l16];
        #pragma unroll
        for (int s=0; s<2; s++){
            d2[s][ot] = __builtin_amdgcn_mfma_f32_16x16x32_bf16(af0[s], bw0, z4, 0,0,0);
            d2[s][ot] = __builtin_amdgcn_mfma_f32_16x16x32_bf16(af1[s], bw1, d2[s][ot], 0,0,0);
            #pragma unroll
            for (int r=0;r<4;r++) d2[s][ot][r] += bias;
        }
    }
    float* sOw = sOT + wv*(64*POT);
    #pragma unroll
    for (int s=0; s<2; s++){
        #pragma unroll
        for (int ot=0; ot<4; ot++){
            #pragma unroll
            for (int r=0;r<4;r++)
                sOw[(ot*16 + l16)*POT + quad*4 + r] = d2[s][ot][r];
        }
        int qbase = qt*128 + wv*32 + s*16;
        #pragma unroll
        for (int it=0; it<16; it++){
            int o = it*4 + quad;
            float val = sOw[o*POT + l16];
            unsafeAtomicAdd(out + ((size_t)(b*64 + o)*128 + h)*512 + qbase + l16, val);
        }
    }
}

extern "C" void kernel_launch(void* const* d_in, const int* in_sizes, int n_in,
                              void* d_out, int out_size, void* d_ws, size_t ws_size,
                              hipStream_t stream)
{
    const float* xl = (const float*)d_in[0];
    const float* xr = (const float*)d_in[1];
    const float* lp1_w1 = (const float*)d_in[2];
    const float* lp1_b1 = (const float*)d_in[3];
    const float* lp1_wd = (const float*)d_in[4];
    const float* lp1_bd = (const float*)d_in[5];
    const float* rp1_w1 = (const float*)d_in[6];
    const float* rp1_b1 = (const float*)d_in[7];
    const float* rp1_wd = (const float*)d_in[8];
    const float* rp1_bd = (const float*)d_in[9];
    const float* lp2_w1 = (const float*)d_in[10];
    const float* lp2_b1 = (const float*)d_in[11];
    const float* lp2_wd = (const float*)d_in[12];
    const float* lp2_bd = (const float*)d_in[13];
    const float* rp2_w1 = (const float*)d_in[14];
    const float* rp2_b1 = (const float*)d_in[15];
    const float* rp2_wd = (const float*)d_in[16];
    const float* rp2_bd = (const float*)d_in[17];
    const float* lp3_w  = (const float*)d_in[18];
    const float* lp3_b  = (const float*)d_in[19];
    const float* rp3_w  = (const float*)d_in[20];
    const float* rp3_b  = (const float*)d_in[21];
    float* out = (float*)d_out;

    // 6 slots of 16 MiB (96 MiB, proven size), slot lifetime choreography:
    //  s0: XtL  -> (dead after gemm)  Ql   (dwL)
    //  s1: XtR  -> (dead after gemm)  Vl   (dwL)
    //  s2: T1L  -> (dead after dwL)   Qr   (dwR)
    //  s3: T2L  -> (dead after dwL)   Vr   (dwR)
    //  s4: T1R  (live until dwR)
    //  s5: T2R  (live until dwR)
    const size_t S = 16777216;
    char* ws = (char*)d_ws;
    unsigned short* s0 = (unsigned short*)(ws);
    unsigned short* s1 = (unsigned short*)(ws + 1*S);
    unsigned short* s2 = (unsigned short*)(ws + 2*S);
    unsigned short* s3 = (unsigned short*)(ws + 3*S);
    unsigned short* s4 = (unsigned short*)(ws + 4*S);
    unsigned short* s5 = (unsigned short*)(ws + 5*S);

    prep_k<<<2048, 256, 0, stream>>>(xl, xr, out, /*XtL*/s0, /*XtR*/s1);

    gemm_k<<<1024, 256, 0, stream>>>(/*XtL*/s0, /*XtR*/s1,
        lp1_w1, lp1_b1, lp2_w1, lp2_b1,
        rp1_w1, rp1_b1, rp2_w1, rp2_b1,
        /*T1L*/s2, /*T2L*/s3, /*T1R*/s4, /*T2R*/s5);

    dwconv_k<<<2048, 256, 0, stream>>>(/*T1L*/s2, /*T2L*/s3,
        lp1_wd, lp1_bd, lp2_wd, lp2_bd, /*Ql*/s0, /*Vl*/s1, QSCALE);

    dwconv_k<<<2048, 256, 0, stream>>>(/*T1R*/s4, /*T2R*/s5,
        rp1_wd, rp1_bd, rp2_wd, rp2_bd, /*Qr*/s2, /*Vr*/s3, 1.0f);

    flash_k<<<2048, 256, 0, stream>>>(/*Ql*/s0, /*Qr*/s2, /*Vl*/s1, /*Vr*/s3,
        lp3_w, lp3_b, rp3_w, rp3_b, out);
}